// Round 1
// baseline (348.158 us; speedup 1.0000x reference)
//
#include <hip/hip_runtime.h>
#include <math.h>

#define BB 4
#define HH 384
#define WW 384
#define AH 385
#define AW 385
#define NB 8

static constexpr float EPSV   = 1e-10f;
static constexpr float TWO_PI = 6.283185307179586f;

// ---------------------------------------------------------------------------
// K1: per-pixel gradient -> soft orientation histogram (B,8,H,W)
// ---------------------------------------------------------------------------
__global__ __launch_bounds__(256) void k_hist(const float* __restrict__ x,
                                              float* __restrict__ hist) {
    int idx = blockIdx.x * blockDim.x + threadIdx.x;
    if (idx >= BB * HH * WW) return;
    int px = idx % WW;
    int py = (idx / WW) % HH;
    int b  = idx / (WW * HH);

    const float* xb = x + (size_t)b * HH * WW;
    int xm = max(px - 1, 0), xp = min(px + 1, WW - 1);
    int ym = max(py - 1, 0), yp = min(py + 1, HH - 1);

    float gx = (xb[(size_t)py * WW + xp] - xb[(size_t)py * WW + xm]) * 0.5f;
    float gy = (xb[(size_t)yp * WW + px] - xb[(size_t)ym * WW + px]) * 0.5f;

    float mag  = sqrtf(gx * gx + gy * gy + EPSV);
    float ori  = atan2f(gy, gx + EPSV) + TWO_PI;          // (pi, 3pi]
    float obig = 8.0f * ori / TWO_PI;                      // (4, 12]
    float b0f  = floorf(obig);
    float wo1  = obig - b0f;
    int   ib   = (int)b0f;                                 // 4..12, positive
    int   b0   = ib & 7;
    int   b1   = (ib + 1) & 7;
    float w0   = (1.0f - wo1) * mag;
    float w1   = wo1 * mag;

    float* hb = hist + (size_t)b * NB * HH * WW + (size_t)py * WW + px;
#pragma unroll
    for (int d = 0; d < NB; ++d) {
        float v = (d == b0 ? w0 : 0.0f) + (d == b1 ? w1 : 0.0f);
        hb[(size_t)d * HH * WW] = v;
    }
}

// ---------------------------------------------------------------------------
// K2: depthwise 4x4 triangular pooling, pad 2 -> ang (B,8,385,385)
// ---------------------------------------------------------------------------
__global__ __launch_bounds__(256) void k_pool(const float* __restrict__ hist,
                                              const float* __restrict__ pw,
                                              float* __restrict__ ang) {
    __shared__ float spw[16];
    if (threadIdx.x < 16) spw[threadIdx.x] = pw[threadIdx.x];
    __syncthreads();

    int idx = blockIdx.x * blockDim.x + threadIdx.x;
    if (idx >= BB * NB * AH * AW) return;
    int xx = idx % AW;
    int t  = idx / AW;
    int yy = t % AH;
    t /= AH;                       // t = b*NB + d

    const float* hb = hist + (size_t)t * HH * WW;
    float acc = 0.0f;
#pragma unroll
    for (int i = 0; i < 4; ++i) {
        int hy  = yy - 2 + i;
        int hyc = min(max(hy, 0), HH - 1);
        bool rok = (unsigned)hy < (unsigned)HH;
#pragma unroll
        for (int j = 0; j < 4; ++j) {
            int hx  = xx - 2 + j;
            int hxc = min(max(hx, 0), WW - 1);
            bool ok = rok && ((unsigned)hx < (unsigned)WW);
            float w = ok ? spw[i * 4 + j] : 0.0f;         // mask weight, load stays in-bounds
            acc += w * hb[(size_t)hyc * WW + hxc];
        }
    }
    ang[idx] = acc;
}

// ---------------------------------------------------------------------------
// K3: gather 16 neighbors x 8 channels of ang (the identity "reshape conv"),
//     then L2norm -> clip(0,0.2) -> L2norm -> L1norm -> sqrt(+eps)
// ---------------------------------------------------------------------------
__global__ __launch_bounds__(256) void k_final(const float* __restrict__ ang,
                                               float* __restrict__ out) {
    int idx = blockIdx.x * blockDim.x + threadIdx.x;
    if (idx >= BB * HH * WW) return;
    int px = idx % WW;
    int py = (idx / WW) % HH;
    int b  = idx / (WW * HH);

    float v[128];
    float ss1 = 0.0f;
#pragma unroll
    for (int d = 0; d < 8; ++d) {
        const float* ab = ang + (size_t)(b * NB + d) * AH * AW;
#pragma unroll
        for (int ky = 0; ky < 4; ++ky) {
            int ry   = py - 1 + ky;
            int ryc  = min(max(ry, 0), AH - 1);
            bool rok = (unsigned)ry < (unsigned)AH;
            size_t rowoff = (size_t)ryc * AW;
#pragma unroll
            for (int kx = 0; kx < 4; ++kx) {
                int rx  = px - 1 + kx;
                int rxc = min(max(rx, 0), AW - 1);
                bool ok = rok && ((unsigned)rx < (unsigned)AW);
                float val = ab[rowoff + rxc];
                val = ok ? val : 0.0f;
                v[d * 16 + ky * 4 + kx] = val;
                ss1 += val * val;
            }
        }
    }

    float inv1 = 1.0f / fmaxf(sqrtf(ss1), 1e-12f);
    float ss2 = 0.0f, st = 0.0f;
#pragma unroll
    for (int c = 0; c < 128; ++c) {
        float tv = v[c] * inv1;
        tv = fmaxf(tv, 0.0f);
        tv = fminf(tv, 0.2f);
        v[c] = tv;
        ss2 += tv * tv;
        st  += tv;
    }
    float inv2  = 1.0f / fmaxf(sqrtf(ss2), 1e-12f);
    float s1    = st * inv2;
    float rs1   = 1.0f / fmaxf(s1, 1e-12f);
    float scale = inv2 * rs1;

    float* ob = out + (size_t)b * 128 * HH * WW + (size_t)py * WW + px;
#pragma unroll
    for (int c = 0; c < 128; ++c) {
        ob[(size_t)c * HH * WW] = sqrtf(v[c] * scale + EPSV);
    }
}

// ---------------------------------------------------------------------------
extern "C" void kernel_launch(void* const* d_in, const int* in_sizes, int n_in,
                              void* d_out, int out_size, void* d_ws, size_t ws_size,
                              hipStream_t stream) {
    const float* x  = (const float*)d_in[0];   // (4,1,384,384)
    const float* pw = (const float*)d_in[1];   // (4,4)
    // d_in[2] (reshape_w) is an identity gather; semantics hardcoded in k_final.

    float* hist = (float*)d_ws;                                   // 4*8*384*384 f32 = 18.9 MB
    float* ang  = hist + (size_t)BB * NB * HH * WW;               // 4*8*385*385 f32 = 19.0 MB
    float* out  = (float*)d_out;                                  // (4,128,384,384)

    {
        int total = BB * HH * WW;
        int blocks = (total + 255) / 256;
        k_hist<<<blocks, 256, 0, stream>>>(x, hist);
    }
    {
        int total = BB * NB * AH * AW;
        int blocks = (total + 255) / 256;
        k_pool<<<blocks, 256, 0, stream>>>(hist, pw, ang);
    }
    {
        int total = BB * HH * WW;
        int blocks = (total + 255) / 256;
        k_final<<<blocks, 256, 0, stream>>>(ang, out);
    }
}